// Round 16
// baseline (492.058 us; speedup 1.0000x reference)
//
#include <hip/hip_runtime.h>
#include <hip/hip_bf16.h>
#include <math.h>

#define S 2048
#define D 512
#define H 8
#define DH 64
#define F 2048
#define NLAYER 2

typedef __attribute__((ext_vector_type(8))) short bf16x8;
typedef __attribute__((ext_vector_type(4))) float f32x4;
typedef __hip_bfloat16 bf16;

typedef __attribute__((address_space(3))) unsigned int lds_u32;
typedef __attribute__((address_space(1))) const unsigned int glb_u32;

__device__ __forceinline__ void gld16(const void* g, void* l) {
    __builtin_amdgcn_global_load_lds((glb_u32*)g, (lds_u32*)l, 16, 0, 0);
}

// ---------------- unified prep: all weight transposes + pos-enc + enc cvt ----
__global__ __launch_bounds__(256)
void prep_all(const float* __restrict__ a1w, const float* __restrict__ a2w,
              const float* __restrict__ fw1, const float* __restrict__ fw2,
              bf16* __restrict__ wts,
              const float* __restrict__ x, const float* __restrict__ enc,
              float* __restrict__ xbF, bf16* __restrict__ xbB,
              bf16* __restrict__ encB)
{
    const size_t WCH = 1048576;
    const size_t DD = (size_t)D * D, DF = (size_t)D * F;
    __shared__ float t[64][65];
    const int b = blockIdx.x;
    const int tid = threadIdx.x;

    if (b < 2048) {
        const float* src;
        bf16* dst;
        int R, C, xt, yt;
        if (b < 1024) {
            int m = b >> 6, tt = b & 63;
            xt = tt & 7; yt = tt >> 3;
            R = D; C = D;
            if (m < 8) { src = a1w + (size_t)m * DD; dst = wts + (size_t)(m >> 2) * WCH + (size_t)(m & 3) * DD; }
            else { int m2 = m - 8; src = a2w + (size_t)m2 * DD; dst = wts + 2 * WCH + (size_t)(m2 >> 2) * WCH + (size_t)(m2 & 3) * DD; }
        } else if (b < 1536) {
            int tt = b - 1024;
            int m = tt >> 8; tt &= 255;
            xt = tt & 7; yt = tt >> 3;
            R = D; C = F;
            src = fw1 + (size_t)m * DF; dst = wts + (size_t)(4 + m) * WCH;
        } else {
            int tt = b - 1536;
            int m = tt >> 8; tt &= 255;
            xt = tt & 31; yt = tt >> 5;
            R = F; C = D;
            src = fw2 + (size_t)m * DF; dst = wts + (size_t)(6 + m) * WCH;
        }
        const int rb = xt * 64, cb = yt * 64;
        for (int i = tid; i < 4096; i += 256) {
            int r = i >> 6, c = i & 63;
            t[r][c] = src[(size_t)(rb + r) * C + cb + c];
        }
        __syncthreads();
        for (int i = tid; i < 4096; i += 256) {
            int r = i >> 6, c = i & 63;
            dst[(size_t)(cb + r) * R + rb + c] = __float2bfloat16(t[c][r]);
        }
    } else {
        int idx = (b - 2048) * 256 + tid;
        if (idx < S * D) {
            int s = idx / D;
            int j = idx % D;
            int jj = (j < D / 2) ? j : j - D / 2;
            float rate = expf(-(float)jj * (logf(10000.0f) / (float)(D / 2)));
            float ang = (float)s * rate;
            float pe = (j < D / 2) ? sinf(ang) : cosf(ang);
            float v = x[idx] + pe;
            xbF[idx] = v;
            xbB[idx] = __float2bfloat16(v);
            encB[idx] = __float2bfloat16(enc[idx]);
        }
    }
}

// ---------------- bf16 MFMA GEMM, 2-phase prefetch, BK-deep K-steps ----------------
// out = A[M,K] @ Bt[N,K]^T + bias.  A is per-column-region: Aalt used for
// columns >= qn when MODE==1 (merged q|kv projections).
// MODE 0: plain epilogue -> outF (fp32, ldc) and/or outB (bf16, ldc).
// MODE 1: attention pack -> q16 / kh / vt (vt via LDS bounce).
// MODE 2: fused residual+LayerNorm epilogue (BM=32 only): cross-block row
//         reduction via device-scope atomics (rsumG/rsqG) + counter release;
//         writes outF (fp32) and optional outB (bf16) = LN(xbIn + GEMM+bias).
template<int BM, int BN, int BK, int MODE>
__global__ __launch_bounds__(256)
void gemm_bf16(const bf16* __restrict__ A, const bf16* __restrict__ Aalt,
               const bf16* __restrict__ Bt,
               const float* __restrict__ bias, float* __restrict__ outF,
               bf16* __restrict__ outB, int K, int ldc, int relu,
               bf16* __restrict__ q16, bf16* __restrict__ kh,
               bf16* __restrict__ vt, int qn, int kn,
               const float* __restrict__ xbIn, const float* __restrict__ lgam,
               const float* __restrict__ lbet, float* __restrict__ rsumG,
               float* __restrict__ rsqG, unsigned int* __restrict__ cntG)
{
    constexpr int MI = BM / 32, NJ = BN / 32;
    constexpr int SL = BK / 8;             // 16B slots per LDS row
    constexpr int KS = BK / 32;            // 32-k sub-steps per K-step
    constexpr int HALF = (BM + BN) * BK * 2;
    constexpr int IA = BM * SL / 256, IB = BN * SL / 256;
    constexpr int TS = BN + 8;             // V-bounce scratch stride (shorts)
    constexpr int LDS_VB = (MODE == 1) ? BM * TS * 2 : 0;
    constexpr int LDSZ = (2 * HALF > LDS_VB) ? 2 * HALF : LDS_VB;
    __shared__ char lds[LDSZ];
    const int tid = threadIdx.x;
    const int w = tid >> 6, l = tid & 63;
    const int l15 = l & 15, l4 = l >> 4;
    const int bm = blockIdx.y * BM, bn = blockIdx.x * BN;
    const int wr = (w >> 1) * (BM / 2), wc = (w & 1) * (BN / 2);
    const bf16* Ause = (MODE == 1 && bn >= qn) ? Aalt : A;

    f32x4 acc[MI][NJ] = {};

#define XV(row) ((BK == 64) ? ((row) & 7) : (((row) >> 1) & 3))
#define GSTAGE(k0, b)                                                          \
    {                                                                          \
        _Pragma("unroll")                                                      \
        for (int i = 0; i < IA; ++i) {                                         \
            int n = (w * IA + i) * 64 + l;                                     \
            int row = n / SL;                                                  \
            int sl = (n % SL) ^ XV(row);                                       \
            gld16(Ause + (size_t)(bm + row) * K + (k0) + sl * 8,               \
                  lds + (b) * HALF + (w * IA + i) * 1024);                     \
        }                                                                      \
        _Pragma("unroll")                                                      \
        for (int i = 0; i < IB; ++i) {                                         \
            int n = (w * IB + i) * 64 + l;                                     \
            int row = n / SL;                                                  \
            int sl = (n % SL) ^ XV(row);                                       \
            gld16(Bt + (size_t)(bn + row) * K + (k0) + sl * 8,                 \
                  lds + (b) * HALF + BM * BK * 2 + (w * IB + i) * 1024);       \
        }                                                                      \
    }

    GSTAGE(0, 0);
    __syncthreads();
    int cur = 0;
    for (int k0 = 0; k0 < K; k0 += BK) {
        if (k0 + BK < K) GSTAGE(k0 + BK, cur ^ 1);
        const char* base = lds + cur * HALF;
        bf16x8 af[MI][KS], bfr[NJ][KS];
#pragma unroll
        for (int i = 0; i < MI; ++i) {
            int row = wr + i * 16 + l15;
#pragma unroll
            for (int s = 0; s < KS; ++s)
                af[i][s] = *(const bf16x8*)(base + row * (BK * 2)
                                            + (((s * 4 + l4) ^ XV(row)) << 4));
        }
#pragma unroll
        for (int j = 0; j < NJ; ++j) {
            int row = wc + j * 16 + l15;
#pragma unroll
            for (int s = 0; s < KS; ++s)
                bfr[j][s] = *(const bf16x8*)(base + BM * BK * 2 + row * (BK * 2)
                                             + (((s * 4 + l4) ^ XV(row)) << 4));
        }
#pragma unroll
        for (int s = 0; s < KS; ++s)
#pragma unroll
            for (int i = 0; i < MI; ++i)
#pragma unroll
                for (int j = 0; j < NJ; ++j)
                    acc[i][j] = __builtin_amdgcn_mfma_f32_16x16x32_bf16(af[i][s], bfr[j][s], acc[i][j], 0, 0, 0);
        __syncthreads();
        cur ^= 1;
    }
#undef GSTAGE
#undef XV

    if (MODE == 0) {
#pragma unroll
        for (int i = 0; i < MI; ++i)
#pragma unroll
            for (int j = 0; j < NJ; ++j)
#pragma unroll
                for (int q = 0; q < 4; ++q) {
                    int row = bm + wr + i * 16 + l4 * 4 + q;
                    int col = bn + wc + j * 16 + l15;
                    float v = acc[i][j][q] + bias[col];
                    if (relu) v = fmaxf(v, 0.f);
                    if (outF) outF[(size_t)row * ldc + col] = v;
                    if (outB) outB[(size_t)row * ldc + col] = __float2bfloat16(v);
                }
    } else if (MODE == 1) {
        const int creg = (bn < qn) ? 0 : (bn < qn + kn ? 1 : 2);
        if (creg < 2) {
#pragma unroll
            for (int i = 0; i < MI; ++i)
#pragma unroll
                for (int j = 0; j < NJ; ++j)
#pragma unroll
                    for (int q = 0; q < 4; ++q) {
                        int row = bm + wr + i * 16 + l4 * 4 + q;
                        int col = bn + wc + j * 16 + l15;
                        float v = acc[i][j][q] + bias[col];
                        if (creg == 0) {
                            q16[(size_t)row * 512 + col] = __float2bfloat16(v);
                        } else {
                            int c2 = col - qn;
                            kh[((size_t)(c2 >> 6) * S + row) * 64 + (c2 & 63)] = __float2bfloat16(v);
                        }
                    }
        } else {
            // V region: bounce through LDS, write transposed vt[d][S].
            short* t = (short*)lds;
#pragma unroll
            for (int i = 0; i < MI; ++i)
#pragma unroll
                for (int j = 0; j < NJ; ++j)
#pragma unroll
                    for (int q = 0; q < 4; ++q) {
                        int r = wr + i * 16 + l4 * 4 + q;       // local row (s index)
                        int c = wc + j * 16 + l15;              // local col (d index)
                        float v = acc[i][j][q] + bias[bn + c];
                        t[r * TS + c] = __builtin_bit_cast(short, __float2bfloat16(v));
                    }
            __syncthreads();
            const int dgb = bn - qn - kn;
            constexpr int SGR = BM / 8;     // 8-elem groups per column
            for (int i2 = tid; i2 < BN * SGR; i2 += 256) {
                int dl = i2 / SGR;          // 0..BN-1 (d within tile)
                int s8 = (i2 % SGR) * 8;    // 0..BM-8 (seq start)
                bf16x8 v;
#pragma unroll
                for (int jj = 0; jj < 8; ++jj)
                    v[jj] = t[(s8 + jj) * TS + dl];
                *(bf16x8*)(vt + (size_t)(dgb + dl) * S + bm + s8) = v;
            }
        }
    } else {
        // ---- MODE 2: fused residual + LayerNorm (BM=32, NJ=2, MI=1) ----
        float s_[NJ][4];
        float psum[4], psq[4];
#pragma unroll
        for (int q = 0; q < 4; ++q) { psum[q] = 0.f; psq[q] = 0.f; }
#pragma unroll
        for (int j = 0; j < NJ; ++j)
#pragma unroll
            for (int q = 0; q < 4; ++q) {
                int row = bm + wr + l4 * 4 + q;
                int col = bn + wc + j * 16 + l15;
                float v = acc[0][j][q] + bias[col] + xbIn[(size_t)row * 512 + col];
                s_[j][q] = v;
                psum[q] += v;
                psq[q] += v * v;
            }
        // reduce over the 16 l15 lanes (same rows, 32 cols per wave)
#pragma unroll
        for (int q = 0; q < 4; ++q)
#pragma unroll
            for (int off = 1; off < 16; off <<= 1) {
                psum[q] += __shfl_xor(psum[q], off);
                psq[q]  += __shfl_xor(psq[q], off);
            }
        float* lsum = (float*)lds;            // [32][2]
        float* lsq  = (float*)(lds + 256);    // [32][2]
        float* lmu  = (float*)(lds + 512);    // [32]
        float* lrsv = (float*)(lds + 640);    // [32]
        if (l15 == 0) {
#pragma unroll
            for (int q = 0; q < 4; ++q) {
                int rl = wr + l4 * 4 + q;
                lsum[rl * 2 + (w & 1)] = psum[q];
                lsq [rl * 2 + (w & 1)] = psq[q];
            }
        }
        __syncthreads();
        if (tid < 32) {
            float bs = lsum[tid * 2] + lsum[tid * 2 + 1];
            float bq = lsq [tid * 2] + lsq [tid * 2 + 1];
            atomicAdd(&rsumG[blockIdx.y * 32 + tid], bs);
            atomicAdd(&rsqG [blockIdx.y * 32 + tid], bq);
        }
        __threadfence();
        __syncthreads();
        if (tid == 0) {
            atomicAdd(&cntG[blockIdx.y], 1u);
            while (atomicAdd(&cntG[blockIdx.y], 0u) < 8u)
                __builtin_amdgcn_s_sleep(8);
        }
        __syncthreads();
        if (tid < 32) {
            float ts = atomicAdd(&rsumG[blockIdx.y * 32 + tid], 0.f);
            float tq = atomicAdd(&rsqG [blockIdx.y * 32 + tid], 0.f);
            float mu = ts * (1.f / 512.f);
            float var = tq * (1.f / 512.f) - mu * mu;
            lmu[tid] = mu;
            lrsv[tid] = rsqrtf(var + 1e-6f);
        }
        __syncthreads();
#pragma unroll
        for (int j = 0; j < NJ; ++j)
#pragma unroll
            for (int q = 0; q < 4; ++q) {
                int rl = wr + l4 * 4 + q;
                int row = bm + rl;
                int col = bn + wc + j * 16 + l15;
                float ov = (s_[j][q] - lmu[rl]) * lrsv[rl] * lgam[col] + lbet[col];
                outF[(size_t)row * ldc + col] = ov;
                if (outB) outB[(size_t)row * ldc + col] = __float2bfloat16(ov);
            }
    }
}

// ---------------- 8-wave split-key LDS-staged MFMA flash attention ----------
// Block = 8 waves (512 thr) = one (head, 64-q-row tile). Key-group g = w>>2:
// group 0 handles even 64-key chunks, group 1 odd chunks; wave w owns q-rows
// (w&3)*16. Each group bulk-stages its own chunk's K (head-packed Kh) + V
// (d-major Vt) into its half of a double-buffered 64KB region; one barrier
// per chunk-pair. XOR swizzle both sides (rule 21). Swapped QK^T (mfma(K,Q));
// log2-domain softmax, pre-scaled Q, defer-max. setprio(1) around MFMA
// clusters (T5). End: flash-decoding merge of the 2 per-group partials.
// Grid (H, S/64): same-head blocks cluster for K/V L2 locality.
template<int CAUSAL>
__global__ __launch_bounds__(512)
void attn_mfma7(const bf16* __restrict__ Q, const bf16* __restrict__ Kh,
                const bf16* __restrict__ Vt, bf16* __restrict__ O)
{
    // [0,65536): staging buf[p][g]: p*32768 + g*16384, K @+0 (8KB), V @+8192
    // [65536,81920): P tiles / o-partials, 2KB per wave (8 waves)
    // [81920,82944): m/l strip: wave w at +w*128, q at +q*8
    __shared__ char lds[82944];
    const int tid = threadIdx.x;
    const int w = tid >> 6, l = tid & 63;
    const int l15 = l & 15, l4 = l >> 4;
    const int g = w >> 2, wl = w & 3;
    const int h = blockIdx.x, qb = blockIdx.y;
    const int qw = qb * 64 + wl * 16;
    const int qr = qw + l15;
    char* plds = lds + 65536 + w * 2048;

    // Q fragment from dense q16 [S][512], pre-scaled by 0.125 * log2(e)
    const float QSC = 0.1803368801f;
    bf16x8 aq[2];
#pragma unroll
    for (int s = 0; s < 2; ++s) {
        bf16x8 raw = *(const bf16x8*)(Q + (size_t)(qw + l15) * 512 + h * DH + s * 32 + l4 * 8);
#pragma unroll
        for (int j = 0; j < 8; ++j) {
            float f = __builtin_bit_cast(float, ((unsigned int)(unsigned short)raw[j]) << 16) * QSC;
            raw[j] = __builtin_bit_cast(short, __float2bfloat16(f));
        }
        aq[s] = raw;
    }

    f32x4 o[4] = {};              // o[dt]: q = l4*4+reg, d = dt*16+l15
    float mrun = -1e30f, lrun = 0.f;
    const int cmax = CAUSAL ? qb : (S / 64 - 1);
    const int nits = cmax / 2 + 1;

    // group g stages its chunk 2*ii+g (if in range) into buf[p][g]
#define STAGE(ii, p)                                                                \
    {                                                                               \
        const int cc = 2 * (ii) + g;                                                \
        if (cc <= cmax) {                                                           \
            const int kb2 = cc * 64;                                                \
            _Pragma("unroll")                                                       \
            for (int i = 0; i < 2; ++i) {                                           \
                int n = wl * 128 + i * 64 + l;                                      \
                int row = n >> 3;                                                   \
                int sl = (n & 7) ^ (row & 7);                                       \
                gld16(Kh + ((size_t)h * S + kb2 + row) * 64 + sl * 8,               \
                      lds + (p) * 32768 + g * 16384 + wl * 2048 + i * 1024);        \
                gld16(Vt + ((size_t)(h * 64 + row)) * S + kb2 + sl * 8,             \
                      lds + (p) * 32768 + g * 16384 + 8192 + wl * 2048 + i * 1024); \
            }                                                                       \
        }                                                                           \
    }

    STAGE(0, 0);
    __syncthreads();

    int cur = 0;
    for (int it = 0; it < nits; ++it) {
        if (it + 1 < nits) STAGE(it + 1, cur ^ 1);
        const int c = 2 * it + g;
        if (c <= cmax) {
            const char* kb = lds + cur * 32768 + g * 16384;
            const char* vb = kb + 8192;
            const int kbase = c * 64;

            f32x4 st[4];
            __builtin_amdgcn_s_setprio(1);
#pragma unroll
            for (int t = 0; t < 4; ++t) {
                f32x4 sacc = {0.f, 0.f, 0.f, 0.f};
#pragma unroll
                for (int s = 0; s < 2; ++s) {
                    bf16x8 kf = *(const bf16x8*)(kb + (t * 16 + l15) * 128
                                                 + (((s * 4 + l4) ^ (l15 & 7)) << 4));
                    sacc = __builtin_amdgcn_mfma_f32_16x16x32_bf16(kf, aq[s], sacc, 0, 0, 0);
                }
                st[t] = sacc;
            }
            __builtin_amdgcn_s_setprio(0);

            float mx = -1e30f;
#pragma unroll
            for (int t = 0; t < 4; ++t)
#pragma unroll
                for (int r = 0; r < 4; ++r) {
                    float v = st[t][r];
                    if (CAUSAL && c == cmax) {
                        int key = kbase + t * 16 + l4 * 4 + r;
                        if (key > qr) v = -1e30f;
                    }
                    st[t][r] = v;
                    mx = fmaxf(mx, v);
                }
            mx = fmaxf(mx, __shfl_xor(mx, 16));
            mx = fmaxf(mx, __shfl_xor(mx, 32));

            if (__any(mx > mrun + 8.0f)) {
                float mnew = fmaxf(mrun, mx);
                float scl = exp2f(mrun - mnew);
                mrun = mnew;
                lrun *= scl;
#pragma unroll
                for (int j = 0; j < 4; ++j) {
                    float sj = __shfl(scl, (l & 48) | (l4 * 4 + j));
#pragma unroll
                    for (int dt = 0; dt < 4; ++dt) o[dt][j] *= sj;
                }
            }

            float ps = 0.f;
#pragma unroll
            for (int t = 0; t < 4; ++t) {
                float e0 = exp2f(st[t][0] - mrun);
                float e1 = exp2f(st[t][1] - mrun);
                float e2 = exp2f(st[t][2] - mrun);
                float e3 = exp2f(st[t][3] - mrun);
                ps += (e0 + e1) + (e2 + e3);
                unsigned int lo = (unsigned int)(unsigned short)__builtin_bit_cast(short, __float2bfloat16(e0))
                                | ((unsigned int)(unsigned short)__builtin_bit_cast(short, __float2bfloat16(e1)) << 16);
                unsigned int hi = (unsigned int)(unsigned short)__builtin_bit_cast(short, __float2bfloat16(e2))
                                | ((unsigned int)(unsigned short)__builtin_bit_cast(short, __float2bfloat16(e3)) << 16);
                uint2 pk; pk.x = lo; pk.y = hi;
                int byte = (l15 * 128 + t * 32 + l4 * 8) ^ ((l15 & 7) << 4);
                *(uint2*)(plds + byte) = pk;
            }
            ps += __shfl_xor(ps, 16);
            ps += __shfl_xor(ps, 32);
            lrun += ps;

            bf16x8 pf[2];
#pragma unroll
            for (int s = 0; s < 2; ++s) {
                int byte = (l15 * 128 + s * 64 + l4 * 16) ^ ((l15 & 7) << 4);
                pf[s] = *(const bf16x8*)(plds + byte);
            }
            __builtin_amdgcn_s_setprio(1);
#pragma unroll
            for (int dt = 0; dt < 4; ++dt)
#pragma unroll
                for (int s = 0; s < 2; ++s) {
                    bf16x8 vf = *(const bf16x8*)(vb + (dt * 16 + l15) * 128
                                                 + (((s * 4 + l4) ^ (l15 & 7)) << 4));
                    o[dt] = __builtin_amdgcn_mfma_f32_16x16x32_bf16(pf[s], vf, o[dt], 0, 0, 0);
                }
            __builtin_amdgcn_s_setprio(0);
        }
        __syncthreads();
        cur ^= 1;
    }
#undef STAGE

    // ---- store partials (bf16 over own P tile) + m/l strip ----
#pragma unroll
    for (int dt = 0; dt < 4; ++dt)
#pragma unroll
        for (int j = 0; j < 4; ++j) {
            int q = l4 * 4 + j;
            int d = dt * 16 + l15;
            int byte = q * 128 + ((d * 2) ^ ((q & 7) << 4));
            *(short*)(plds + byte) = __builtin_bit_cast(short, __float2bfloat16(o[dt][j]));
        }
    if (l < 16) {
        *(float*)(lds + 81920 + w * 128 + l * 8) = mrun;
        *(float*)(lds + 81920 + w * 128 + l * 8 + 4) = lrun;
    }
    __syncthreads();

    // ---- merge 2 group-partials: 512 threads; t -> (q-subtile, q, d0) ----
    {
        const int qt16 = tid >> 7;          // 0..3
        const int idx = tid & 127;
        const int q = idx >> 3;             // 0..15
        const int d0 = (idx & 7) * 8;       // 0,8,..,56
        const char* p0 = lds + 65536 + qt16 * 2048;
        const char* p1 = lds + 65536 + (qt16 + 4) * 2048;
        float m0 = *(const float*)(lds + 81920 + qt16 * 128 + q * 8);
        float l0 = *(const float*)(lds + 81920 + qt16 * 128 + q * 8 + 4);
        float m1 = *(const float*)(lds + 81920 + (qt16 + 4) * 128 + q * 8);
        float l1 = *(const float*)(lds + 81920 + (qt16 + 4) * 128 + q * 8 + 4);
        float mt = fmaxf(m0, m1);
        float f0 = exp2f(m0 - mt), f1 = exp2f(m1 - mt);
        float lt = f0 * l0 + f1 * l1;
        float inv = 1.f / lt;
        int byte = q * 128 + ((d0 * 2) ^ ((q & 7) << 4));
        bf16x8 a = *(const bf16x8*)(p0 + byte);
        bf16x8 b = *(const bf16x8*)(p1 + byte);
        bf16x8 r;
#pragma unroll
        for (int jj = 0; jj < 8; ++jj) {
            float va = __builtin_bit_cast(float, ((unsigned int)(unsigned short)a[jj]) << 16);
            float vb2 = __builtin_bit_cast(float, ((unsigned int)(unsigned short)b[jj]) << 16);
            r[jj] = __builtin_bit_cast(short, __float2bfloat16((f0 * va + f1 * vb2) * inv));
        }
        *(bf16x8*)(O + (size_t)(qb * 64 + qt16 * 16 + q) * D + h * DH + d0) = r;
    }
}

extern "C" void kernel_launch(void* const* d_in, const int* in_sizes, int n_in,
                              void* d_out, int out_size, void* d_ws, size_t ws_size,
                              hipStream_t stream)
{
    const float* x   = (const float*)d_in[0];
    const float* enc = (const float*)d_in[1];
    const float* a1w = (const float*)d_in[2];
    const float* a1b = (const float*)d_in[3];
    const float* a2w = (const float*)d_in[4];
    const float* a2b = (const float*)d_in[5];
    const float* fw1 = (const float*)d_in[6];
    const float* fb1 = (const float*)d_in[7];
    const float* fw2 = (const float*)d_in[8];
    const float* fb2 = (const float*)d_in[9];
    const float* lng = (const float*)d_in[10];
    const float* lnb = (const float*)d_in[11];
    float* out = (float*)d_out;

    char* wsb = (char*)d_ws;
    float* xb   = (float*)(wsb);                       // 4 MB @0
    bf16* xb16  = (bf16*)(wsb + ((size_t)8 << 20));    // 2 MB @8M
    bf16* enc16 = (bf16*)(wsb + ((size_t)10 << 20));   // 2 MB @10M
    bf16* att16 = (bf16*)(wsb + ((size_t)12 << 20));   // 2 MB @12M
    bf16* q16   = (bf16*)(wsb + ((size_t)14 << 20));   // 2 MB @14M
    bf16* kh16  = (bf16*)(wsb + ((size_t)16 << 20));   // 2 MB @16M
    bf16* vt16  = (bf16*)(wsb + ((size_t)18 << 20));   // 2 MB @18M
    bf16* ffh16 = att16;                               // 8 MB @12M (aliases attn bufs; disjoint lifetime)
    bf16* wts   = (bf16*)(wsb + ((size_t)20 << 20));   // 16 MB @20M
    char* lnsc  = wsb + ((size_t)36 << 20);            // 192 KB @36M: 6 x 32KB LN scratch
    const size_t WCH = 1048576;
    const size_t DD = (size_t)D * D;

    // zero the fused-LN scratch (rowsum/rowsq/counters) — handles 0xAA poison
    hipMemsetAsync(lnsc, 0, 6 * 32768, stream);

    // ---- unified prep: all weight transposes + pos-enc + enc cvt (1 dispatch) ----
    prep_all<<<6144, 256, 0, stream>>>(a1w, a2w, fw1, fw2, wts, x, enc, xb, xb16, enc16);

    for (int l = 0; l < NLAYER; ++l) {
        const bf16* A1T = wts + (size_t)(0 + l) * WCH;
        const bf16* A2T = wts + (size_t)(2 + l) * WCH;
        const bf16* W1T = wts + (size_t)(4 + l) * WCH;
        const bf16* W2T = wts + (size_t)(6 + l) * WCH;
        const float* b1v = a1b + (size_t)l * 4 * D;
        const float* b2v = a2b + (size_t)l * 4 * D;

#define LNSCRATCH(k) (float*)(lnsc + (size_t)(l * 3 + (k)) * 32768),              \
                     (float*)(lnsc + (size_t)(l * 3 + (k)) * 32768 + 8192),       \
                     (unsigned int*)(lnsc + (size_t)(l * 3 + (k)) * 32768 + 16384)

        // self-attention: fused QKV GEMM writes q16/kh16/vt16 directly
        gemm_bf16<64, 64, 64, 1><<<dim3(24, 32), 256, 0, stream>>>(
            xb16, xb16, A1T, b1v, nullptr, nullptr, D, 0, 0, q16, kh16, vt16, 512, 512,
            nullptr, nullptr, nullptr, nullptr, nullptr, nullptr);
        attn_mfma7<1><<<dim3(H, S / 64), 512, 0, stream>>>(q16, kh16, vt16, att16);
        // wo-GEMM with fused residual+LN epilogue -> xb, xb16
        gemm_bf16<32, 64, 64, 2><<<dim3(8, 64), 256, 0, stream>>>(
            att16, att16, A1T + 3 * DD, b1v + 3 * D, xb, xb16, D, D, 0,
            nullptr, nullptr, nullptr, 0, 0,
            xb, lng + (size_t)(l * 3 + 0) * D, lnb + (size_t)(l * 3 + 0) * D, LNSCRATCH(0));

        // cross-attention: merged q|kv projection (q from xb16, k/v from enc16)
        gemm_bf16<64, 64, 64, 1><<<dim3(24, 32), 256, 0, stream>>>(
            xb16, enc16, A2T, b2v, nullptr, nullptr, D, 0, 0, q16, kh16, vt16, 512, 512,
            nullptr, nullptr, nullptr, nullptr, nullptr, nullptr);
        attn_mfma7<0><<<dim3(H, S / 64), 512, 0, stream>>>(q16, kh16, vt16, att16);
        gemm_bf16<32, 64, 64, 2><<<dim3(8, 64), 256, 0, stream>>>(
            att16, att16, A2T + 3 * DD, b2v + 3 * D, xb, xb16, D, D, 0,
            nullptr, nullptr, nullptr, 0, 0,
            xb, lng + (size_t)(l * 3 + 1) * D, lnb + (size_t)(l * 3 + 1) * D, LNSCRATCH(1));

        // FFN
        gemm_bf16<64, 64, 64, 0><<<dim3(32, 32), 256, 0, stream>>>(
            xb16, xb16, W1T, fb1 + (size_t)l * F, nullptr, ffh16, D, F, 1,
            nullptr, nullptr, nullptr, 0, 0,
            nullptr, nullptr, nullptr, nullptr, nullptr, nullptr);
        float* dstF = (l == NLAYER - 1) ? out : xb;
        bf16* dstB = (l == NLAYER - 1) ? nullptr : xb16;
        gemm_bf16<32, 64, 64, 2><<<dim3(8, 64), 256, 0, stream>>>(
            ffh16, ffh16, W2T, fb2 + (size_t)l * D, dstF, dstB, F, D, 0,
            nullptr, nullptr, nullptr, 0, 0,
            xb, lng + (size_t)(l * 3 + 2) * D, lnb + (size_t)(l * 3 + 2) * D, LNSCRATCH(2));
#undef LNSCRATCH
    }
}

// Round 17
// 266.442 us; speedup vs baseline: 1.8468x; 1.8468x over previous
//
#include <hip/hip_runtime.h>
#include <hip/hip_bf16.h>
#include <math.h>

#define S 2048
#define D 512
#define H 8
#define DH 64
#define F 2048
#define NLAYER 2

typedef __attribute__((ext_vector_type(8))) short bf16x8;
typedef __attribute__((ext_vector_type(4))) float f32x4;
typedef __hip_bfloat16 bf16;

typedef __attribute__((address_space(3))) unsigned int lds_u32;
typedef __attribute__((address_space(1))) const unsigned int glb_u32;

__device__ __forceinline__ void gld16(const void* g, void* l) {
    __builtin_amdgcn_global_load_lds((glb_u32*)g, (lds_u32*)l, 16, 0, 0);
}

// ---------------- unified prep: all weight transposes + pos-enc + enc cvt ----
// Flat 1D grid, 256 thr/block, roles by block id:
//   [0,1024):    attn-weight transpose tiles (16 mats x 64 tiles)
//   [1024,1536): fw1 transpose (2 mats x 256 tiles)
//   [1536,2048): fw2 transpose (2 mats x 256 tiles)
//   [2048,6144): pos-enc add + bf16 mirrors (4096 blocks over S*D)
__global__ __launch_bounds__(256)
void prep_all(const float* __restrict__ a1w, const float* __restrict__ a2w,
              const float* __restrict__ fw1, const float* __restrict__ fw2,
              bf16* __restrict__ wts,
              const float* __restrict__ x, const float* __restrict__ enc,
              float* __restrict__ xbF, bf16* __restrict__ xbB,
              bf16* __restrict__ encB)
{
    const size_t WCH = 1048576;
    const size_t DD = (size_t)D * D, DF = (size_t)D * F;
    __shared__ float t[64][65];
    const int b = blockIdx.x;
    const int tid = threadIdx.x;

    if (b < 2048) {
        const float* src;
        bf16* dst;
        int R, C, xt, yt;
        if (b < 1024) {
            int m = b >> 6, tt = b & 63;
            xt = tt & 7; yt = tt >> 3;
            R = D; C = D;
            if (m < 8) { src = a1w + (size_t)m * DD; dst = wts + (size_t)(m >> 2) * WCH + (size_t)(m & 3) * DD; }
            else { int m2 = m - 8; src = a2w + (size_t)m2 * DD; dst = wts + 2 * WCH + (size_t)(m2 >> 2) * WCH + (size_t)(m2 & 3) * DD; }
        } else if (b < 1536) {
            int tt = b - 1024;
            int m = tt >> 8; tt &= 255;
            xt = tt & 7; yt = tt >> 3;
            R = D; C = F;
            src = fw1 + (size_t)m * DF; dst = wts + (size_t)(4 + m) * WCH;
        } else {
            int tt = b - 1536;
            int m = tt >> 8; tt &= 255;
            xt = tt & 31; yt = tt >> 5;
            R = F; C = D;
            src = fw2 + (size_t)m * DF; dst = wts + (size_t)(6 + m) * WCH;
        }
        const int rb = xt * 64, cb = yt * 64;
        for (int i = tid; i < 4096; i += 256) {
            int r = i >> 6, c = i & 63;
            t[r][c] = src[(size_t)(rb + r) * C + cb + c];
        }
        __syncthreads();
        for (int i = tid; i < 4096; i += 256) {
            int r = i >> 6, c = i & 63;
            dst[(size_t)(cb + r) * R + rb + c] = __float2bfloat16(t[c][r]);
        }
    } else {
        int idx = (b - 2048) * 256 + tid;
        if (idx < S * D) {
            int s = idx / D;
            int j = idx % D;
            int jj = (j < D / 2) ? j : j - D / 2;
            float rate = expf(-(float)jj * (logf(10000.0f) / (float)(D / 2)));
            float ang = (float)s * rate;
            float pe = (j < D / 2) ? sinf(ang) : cosf(ang);
            float v = x[idx] + pe;
            xbF[idx] = v;
            xbB[idx] = __float2bfloat16(v);
            encB[idx] = __float2bfloat16(enc[idx]);
        }
    }
}

// ---------------- bf16 MFMA GEMM, 2-phase prefetch, BK-deep K-steps ----------------
// out = A[M,K] @ Bt[N,K]^T + bias.  A is per-column-region: Aalt used for
// columns >= qn when MODE==1 (merged q|kv projections).
// MODE 0: plain epilogue -> outF (fp32, ldc) and/or outB (bf16, ldc).
// MODE 1: attention pack -> cols [0,qn) to q16 [S][512]; [qn,qn+kn) to
//         kh[head][S][64]; rest to vt[d][S] (LDS bounce, [BM][BN+8] scratch).
template<int BM, int BN, int BK, int MODE>
__global__ __launch_bounds__(256)
void gemm_bf16(const bf16* __restrict__ A, const bf16* __restrict__ Aalt,
               const bf16* __restrict__ Bt,
               const float* __restrict__ bias, float* __restrict__ outF,
               bf16* __restrict__ outB, int K, int ldc, int relu,
               bf16* __restrict__ q16, bf16* __restrict__ kh,
               bf16* __restrict__ vt, int qn, int kn)
{
    constexpr int MI = BM / 32, NJ = BN / 32;
    constexpr int SL = BK / 8;             // 16B slots per LDS row
    constexpr int KS = BK / 32;            // 32-k sub-steps per K-step
    constexpr int HALF = (BM + BN) * BK * 2;
    constexpr int IA = BM * SL / 256, IB = BN * SL / 256;
    constexpr int TS = BN + 8;             // V-bounce scratch stride (shorts)
    constexpr int LDS_VB = (MODE == 1) ? BM * TS * 2 : 0;
    constexpr int LDSZ = (2 * HALF > LDS_VB) ? 2 * HALF : LDS_VB;
    __shared__ char lds[LDSZ];
    const int tid = threadIdx.x;
    const int w = tid >> 6, l = tid & 63;
    const int l15 = l & 15, l4 = l >> 4;
    const int bm = blockIdx.y * BM, bn = blockIdx.x * BN;
    const int wr = (w >> 1) * (BM / 2), wc = (w & 1) * (BN / 2);
    const bf16* Ause = (MODE == 1 && bn >= qn) ? Aalt : A;

    f32x4 acc[MI][NJ] = {};

#define XV(row) ((BK == 64) ? ((row) & 7) : (((row) >> 1) & 3))
#define GSTAGE(k0, b)                                                          \
    {                                                                          \
        _Pragma("unroll")                                                      \
        for (int i = 0; i < IA; ++i) {                                         \
            int n = (w * IA + i) * 64 + l;                                     \
            int row = n / SL;                                                  \
            int sl = (n % SL) ^ XV(row);                                       \
            gld16(Ause + (size_t)(bm + row) * K + (k0) + sl * 8,               \
                  lds + (b) * HALF + (w * IA + i) * 1024);                     \
        }                                                                      \
        _Pragma("unroll")                                                      \
        for (int i = 0; i < IB; ++i) {                                         \
            int n = (w * IB + i) * 64 + l;                                     \
            int row = n / SL;                                                  \
            int sl = (n % SL) ^ XV(row);                                       \
            gld16(Bt + (size_t)(bn + row) * K + (k0) + sl * 8,                 \
                  lds + (b) * HALF + BM * BK * 2 + (w * IB + i) * 1024);       \
        }                                                                      \
    }

    GSTAGE(0, 0);
    __syncthreads();
    int cur = 0;
    for (int k0 = 0; k0 < K; k0 += BK) {
        if (k0 + BK < K) GSTAGE(k0 + BK, cur ^ 1);
        const char* base = lds + cur * HALF;
        bf16x8 af[MI][KS], bfr[NJ][KS];
#pragma unroll
        for (int i = 0; i < MI; ++i) {
            int row = wr + i * 16 + l15;
#pragma unroll
            for (int s = 0; s < KS; ++s)
                af[i][s] = *(const bf16x8*)(base + row * (BK * 2)
                                            + (((s * 4 + l4) ^ XV(row)) << 4));
        }
#pragma unroll
        for (int j = 0; j < NJ; ++j) {
            int row = wc + j * 16 + l15;
#pragma unroll
            for (int s = 0; s < KS; ++s)
                bfr[j][s] = *(const bf16x8*)(base + BM * BK * 2 + row * (BK * 2)
                                             + (((s * 4 + l4) ^ XV(row)) << 4));
        }
#pragma unroll
        for (int s = 0; s < KS; ++s)
#pragma unroll
            for (int i = 0; i < MI; ++i)
#pragma unroll
                for (int j = 0; j < NJ; ++j)
                    acc[i][j] = __builtin_amdgcn_mfma_f32_16x16x32_bf16(af[i][s], bfr[j][s], acc[i][j], 0, 0, 0);
        __syncthreads();
        cur ^= 1;
    }
#undef GSTAGE
#undef XV

    if (MODE == 0) {
#pragma unroll
        for (int i = 0; i < MI; ++i)
#pragma unroll
            for (int j = 0; j < NJ; ++j)
#pragma unroll
                for (int q = 0; q < 4; ++q) {
                    int row = bm + wr + i * 16 + l4 * 4 + q;
                    int col = bn + wc + j * 16 + l15;
                    float v = acc[i][j][q] + bias[col];
                    if (relu) v = fmaxf(v, 0.f);
                    if (outF) outF[(size_t)row * ldc + col] = v;
                    if (outB) outB[(size_t)row * ldc + col] = __float2bfloat16(v);
                }
    } else {
        const int creg = (bn < qn) ? 0 : (bn < qn + kn ? 1 : 2);
        if (creg < 2) {
#pragma unroll
            for (int i = 0; i < MI; ++i)
#pragma unroll
                for (int j = 0; j < NJ; ++j)
#pragma unroll
                    for (int q = 0; q < 4; ++q) {
                        int row = bm + wr + i * 16 + l4 * 4 + q;
                        int col = bn + wc + j * 16 + l15;
                        float v = acc[i][j][q] + bias[col];
                        if (creg == 0) {
                            q16[(size_t)row * 512 + col] = __float2bfloat16(v);
                        } else {
                            int c2 = col - qn;
                            kh[((size_t)(c2 >> 6) * S + row) * 64 + (c2 & 63)] = __float2bfloat16(v);
                        }
                    }
        } else {
            // V region: bounce through LDS, write transposed vt[d][S].
            short* t = (short*)lds;
#pragma unroll
            for (int i = 0; i < MI; ++i)
#pragma unroll
                for (int j = 0; j < NJ; ++j)
#pragma unroll
                    for (int q = 0; q < 4; ++q) {
                        int r = wr + i * 16 + l4 * 4 + q;       // local row (s index)
                        int c = wc + j * 16 + l15;              // local col (d index)
                        float v = acc[i][j][q] + bias[bn + c];
                        t[r * TS + c] = __builtin_bit_cast(short, __float2bfloat16(v));
                    }
            __syncthreads();
            const int dgb = bn - qn - kn;
            constexpr int SGR = BM / 8;     // 8-elem groups per column
            for (int i2 = tid; i2 < BN * SGR; i2 += 256) {
                int dl = i2 / SGR;          // 0..BN-1 (d within tile)
                int s8 = (i2 % SGR) * 8;    // 0..BM-8 (seq start)
                bf16x8 v;
#pragma unroll
                for (int jj = 0; jj < 8; ++jj)
                    v[jj] = t[(s8 + jj) * TS + dl];
                *(bf16x8*)(vt + (size_t)(dgb + dl) * S + bm + s8) = v;
            }
        }
    }
}

// ---------------- 8-wave split-key LDS-staged MFMA flash attention ----------
// Block = 8 waves (512 thr) = one (head, 64-q-row tile). Key-group g = w>>2:
// group 0 handles even 64-key chunks, group 1 odd chunks; wave w owns q-rows
// (w&3)*16. Each group bulk-stages its own chunk's K (head-packed Kh) + V
// (d-major Vt) into its half of a double-buffered 64KB region; one barrier
// per chunk-pair. XOR swizzle both sides (rule 21). Swapped QK^T (mfma(K,Q));
// log2-domain softmax, pre-scaled Q, defer-max. setprio(1) around MFMA
// clusters (T5). End: flash-decoding merge of the 2 per-group partials.
// Grid (H, S/64): same-head blocks cluster for K/V L2 locality.
template<int CAUSAL>
__global__ __launch_bounds__(512)
void attn_mfma7(const bf16* __restrict__ Q, const bf16* __restrict__ Kh,
                const bf16* __restrict__ Vt, bf16* __restrict__ O)
{
    // [0,65536): staging buf[p][g]: p*32768 + g*16384, K @+0 (8KB), V @+8192
    // [65536,81920): P tiles / o-partials, 2KB per wave (8 waves)
    // [81920,82944): m/l strip: wave w at +w*128, q at +q*8
    __shared__ char lds[82944];
    const int tid = threadIdx.x;
    const int w = tid >> 6, l = tid & 63;
    const int l15 = l & 15, l4 = l >> 4;
    const int g = w >> 2, wl = w & 3;
    const int h = blockIdx.x, qb = blockIdx.y;
    const int qw = qb * 64 + wl * 16;
    const int qr = qw + l15;
    char* plds = lds + 65536 + w * 2048;

    // Q fragment from dense q16 [S][512], pre-scaled by 0.125 * log2(e)
    const float QSC = 0.1803368801f;
    bf16x8 aq[2];
#pragma unroll
    for (int s = 0; s < 2; ++s) {
        bf16x8 raw = *(const bf16x8*)(Q + (size_t)(qw + l15) * 512 + h * DH + s * 32 + l4 * 8);
#pragma unroll
        for (int j = 0; j < 8; ++j) {
            float f = __builtin_bit_cast(float, ((unsigned int)(unsigned short)raw[j]) << 16) * QSC;
            raw[j] = __builtin_bit_cast(short, __float2bfloat16(f));
        }
        aq[s] = raw;
    }

    f32x4 o[4] = {};              // o[dt]: q = l4*4+reg, d = dt*16+l15
    float mrun = -1e30f, lrun = 0.f;
    const int cmax = CAUSAL ? qb : (S / 64 - 1);
    const int nits = cmax / 2 + 1;

    // group g stages its chunk 2*ii+g (if in range) into buf[p][g]
#define STAGE(ii, p)                                                                \
    {                                                                               \
        const int cc = 2 * (ii) + g;                                                \
        if (cc <= cmax) {                                                           \
            const int kb2 = cc * 64;                                                \
            _Pragma("unroll")                                                       \
            for (int i = 0; i < 2; ++i) {                                           \
                int n = wl * 128 + i * 64 + l;                                      \
                int row = n >> 3;                                                   \
                int sl = (n & 7) ^ (row & 7);                                       \
                gld16(Kh + ((size_t)h * S + kb2 + row) * 64 + sl * 8,               \
                      lds + (p) * 32768 + g * 16384 + wl * 2048 + i * 1024);        \
                gld16(Vt + ((size_t)(h * 64 + row)) * S + kb2 + sl * 8,             \
                      lds + (p) * 32768 + g * 16384 + 8192 + wl * 2048 + i * 1024); \
            }                                                                       \
        }                                                                           \
    }

    STAGE(0, 0);
    __syncthreads();

    int cur = 0;
    for (int it = 0; it < nits; ++it) {
        if (it + 1 < nits) STAGE(it + 1, cur ^ 1);
        const int c = 2 * it + g;
        if (c <= cmax) {
            const char* kb = lds + cur * 32768 + g * 16384;
            const char* vb = kb + 8192;
            const int kbase = c * 64;

            f32x4 st[4];
            __builtin_amdgcn_s_setprio(1);
#pragma unroll
            for (int t = 0; t < 4; ++t) {
                f32x4 sacc = {0.f, 0.f, 0.f, 0.f};
#pragma unroll
                for (int s = 0; s < 2; ++s) {
                    bf16x8 kf = *(const bf16x8*)(kb + (t * 16 + l15) * 128
                                                 + (((s * 4 + l4) ^ (l15 & 7)) << 4));
                    sacc = __builtin_amdgcn_mfma_f32_16x16x32_bf16(kf, aq[s], sacc, 0, 0, 0);
                }
                st[t] = sacc;
            }
            __builtin_amdgcn_s_setprio(0);

            float mx = -1e30f;
#pragma unroll
            for (int t = 0; t < 4; ++t)
#pragma unroll
                for (int r = 0; r < 4; ++r) {
                    float v = st[t][r];
                    if (CAUSAL && c == cmax) {
                        int key = kbase + t * 16 + l4 * 4 + r;
                        if (key > qr) v = -1e30f;
                    }
                    st[t][r] = v;
                    mx = fmaxf(mx, v);
                }
            mx = fmaxf(mx, __shfl_xor(mx, 16));
            mx = fmaxf(mx, __shfl_xor(mx, 32));

            if (__any(mx > mrun + 8.0f)) {
                float mnew = fmaxf(mrun, mx);
                float scl = exp2f(mrun - mnew);
                mrun = mnew;
                lrun *= scl;
#pragma unroll
                for (int j = 0; j < 4; ++j) {
                    float sj = __shfl(scl, (l & 48) | (l4 * 4 + j));
#pragma unroll
                    for (int dt = 0; dt < 4; ++dt) o[dt][j] *= sj;
                }
            }

            float ps = 0.f;
#pragma unroll
            for (int t = 0; t < 4; ++t) {
                float e0 = exp2f(st[t][0] - mrun);
                float e1 = exp2f(st[t][1] - mrun);
                float e2 = exp2f(st[t][2] - mrun);
                float e3 = exp2f(st[t][3] - mrun);
                ps += (e0 + e1) + (e2 + e3);
                unsigned int lo = (unsigned int)(unsigned short)__builtin_bit_cast(short, __float2bfloat16(e0))
                                | ((unsigned int)(unsigned short)__builtin_bit_cast(short, __float2bfloat16(e1)) << 16);
                unsigned int hi = (unsigned int)(unsigned short)__builtin_bit_cast(short, __float2bfloat16(e2))
                                | ((unsigned int)(unsigned short)__builtin_bit_cast(short, __float2bfloat16(e3)) << 16);
                uint2 pk; pk.x = lo; pk.y = hi;
                int byte = (l15 * 128 + t * 32 + l4 * 8) ^ ((l15 & 7) << 4);
                *(uint2*)(plds + byte) = pk;
            }
            ps += __shfl_xor(ps, 16);
            ps += __shfl_xor(ps, 32);
            lrun += ps;

            bf16x8 pf[2];
#pragma unroll
            for (int s = 0; s < 2; ++s) {
                int byte = (l15 * 128 + s * 64 + l4 * 16) ^ ((l15 & 7) << 4);
                pf[s] = *(const bf16x8*)(plds + byte);
            }
            __builtin_amdgcn_s_setprio(1);
#pragma unroll
            for (int dt = 0; dt < 4; ++dt)
#pragma unroll
                for (int s = 0; s < 2; ++s) {
                    bf16x8 vf = *(const bf16x8*)(vb + (dt * 16 + l15) * 128
                                                 + (((s * 4 + l4) ^ (l15 & 7)) << 4));
                    o[dt] = __builtin_amdgcn_mfma_f32_16x16x32_bf16(pf[s], vf, o[dt], 0, 0, 0);
                }
            __builtin_amdgcn_s_setprio(0);
        }
        __syncthreads();
        cur ^= 1;
    }
#undef STAGE

    // ---- store partials (bf16 over own P tile) + m/l strip ----
#pragma unroll
    for (int dt = 0; dt < 4; ++dt)
#pragma unroll
        for (int j = 0; j < 4; ++j) {
            int q = l4 * 4 + j;
            int d = dt * 16 + l15;
            int byte = q * 128 + ((d * 2) ^ ((q & 7) << 4));
            *(short*)(plds + byte) = __builtin_bit_cast(short, __float2bfloat16(o[dt][j]));
        }
    if (l < 16) {
        *(float*)(lds + 81920 + w * 128 + l * 8) = mrun;
        *(float*)(lds + 81920 + w * 128 + l * 8 + 4) = lrun;
    }
    __syncthreads();

    // ---- merge 2 group-partials: 512 threads; t -> (q-subtile, q, d0) ----
    {
        const int qt16 = tid >> 7;          // 0..3
        const int idx = tid & 127;
        const int q = idx >> 3;             // 0..15
        const int d0 = (idx & 7) * 8;       // 0,8,..,56
        const char* p0 = lds + 65536 + qt16 * 2048;
        const char* p1 = lds + 65536 + (qt16 + 4) * 2048;
        float m0 = *(const float*)(lds + 81920 + qt16 * 128 + q * 8);
        float l0 = *(const float*)(lds + 81920 + qt16 * 128 + q * 8 + 4);
        float m1 = *(const float*)(lds + 81920 + (qt16 + 4) * 128 + q * 8);
        float l1 = *(const float*)(lds + 81920 + (qt16 + 4) * 128 + q * 8 + 4);
        float mt = fmaxf(m0, m1);
        float f0 = exp2f(m0 - mt), f1 = exp2f(m1 - mt);
        float lt = f0 * l0 + f1 * l1;
        float inv = 1.f / lt;
        int byte = q * 128 + ((d0 * 2) ^ ((q & 7) << 4));
        bf16x8 a = *(const bf16x8*)(p0 + byte);
        bf16x8 b = *(const bf16x8*)(p1 + byte);
        bf16x8 r;
#pragma unroll
        for (int jj = 0; jj < 8; ++jj) {
            float va = __builtin_bit_cast(float, ((unsigned int)(unsigned short)a[jj]) << 16);
            float vb2 = __builtin_bit_cast(float, ((unsigned int)(unsigned short)b[jj]) << 16);
            r[jj] = __builtin_bit_cast(short, __float2bfloat16((f0 * va + f1 * vb2) * inv));
        }
        *(bf16x8*)(O + (size_t)(qb * 64 + qt16 * 16 + q) * D + h * DH + d0) = r;
    }
}

// ---------------- residual add + layernorm (fp32, optional bf16 mirror) ----------------
__global__ __launch_bounds__(128)
void add_ln_kernel(const float* __restrict__ a, const float* __restrict__ b,
                   const float* __restrict__ g, const float* __restrict__ beta,
                   float* __restrict__ outF, bf16* __restrict__ outB)
{
    const int row = blockIdx.x;
    const int tid = threadIdx.x;
    float4 av = *(const float4*)&a[(size_t)row * D + tid * 4];
    float4 bv = *(const float4*)&b[(size_t)row * D + tid * 4];
    float4 s;
    s.x = av.x + bv.x; s.y = av.y + bv.y; s.z = av.z + bv.z; s.w = av.w + bv.w;
    float sum = s.x + s.y + s.z + s.w;
    float sq = s.x * s.x + s.y * s.y + s.z * s.z + s.w * s.w;
#pragma unroll
    for (int off = 32; off > 0; off >>= 1) {
        sum += __shfl_xor(sum, off);
        sq  += __shfl_xor(sq, off);
    }
    __shared__ float red[4];
    if ((tid & 63) == 0) { red[(tid >> 6) * 2] = sum; red[(tid >> 6) * 2 + 1] = sq; }
    __syncthreads();
    sum = red[0] + red[2];
    sq  = red[1] + red[3];
    float mu = sum / (float)D;
    float var = sq / (float)D - mu * mu;
    float rs = rsqrtf(var + 1e-6f);
    float4 gv = *(const float4*)&g[tid * 4];
    float4 bt = *(const float4*)&beta[tid * 4];
    float4 o;
    o.x = (s.x - mu) * rs * gv.x + bt.x;
    o.y = (s.y - mu) * rs * gv.y + bt.y;
    o.z = (s.z - mu) * rs * gv.z + bt.z;
    o.w = (s.w - mu) * rs * gv.w + bt.w;
    *(float4*)&outF[(size_t)row * D + tid * 4] = o;
    if (outB) {
        outB[(size_t)row * D + tid * 4 + 0] = __float2bfloat16(o.x);
        outB[(size_t)row * D + tid * 4 + 1] = __float2bfloat16(o.y);
        outB[(size_t)row * D + tid * 4 + 2] = __float2bfloat16(o.z);
        outB[(size_t)row * D + tid * 4 + 3] = __float2bfloat16(o.w);
    }
}

extern "C" void kernel_launch(void* const* d_in, const int* in_sizes, int n_in,
                              void* d_out, int out_size, void* d_ws, size_t ws_size,
                              hipStream_t stream)
{
    const float* x   = (const float*)d_in[0];
    const float* enc = (const float*)d_in[1];
    const float* a1w = (const float*)d_in[2];
    const float* a1b = (const float*)d_in[3];
    const float* a2w = (const float*)d_in[4];
    const float* a2b = (const float*)d_in[5];
    const float* fw1 = (const float*)d_in[6];
    const float* fb1 = (const float*)d_in[7];
    const float* fw2 = (const float*)d_in[8];
    const float* fb2 = (const float*)d_in[9];
    const float* lng = (const float*)d_in[10];
    const float* lnb = (const float*)d_in[11];
    float* out = (float*)d_out;

    char* wsb = (char*)d_ws;
    float* xb   = (float*)(wsb);                       // 4 MB @0
    float* ao   = (float*)(wsb + ((size_t)4 << 20));   // 4 MB @4M
    bf16* xb16  = (bf16*)(wsb + ((size_t)8 << 20));    // 2 MB @8M
    bf16* enc16 = (bf16*)(wsb + ((size_t)10 << 20));   // 2 MB @10M
    bf16* att16 = (bf16*)(wsb + ((size_t)12 << 20));   // 2 MB @12M
    bf16* q16   = (bf16*)(wsb + ((size_t)14 << 20));   // 2 MB @14M
    bf16* kh16  = (bf16*)(wsb + ((size_t)16 << 20));   // 2 MB @16M
    bf16* vt16  = (bf16*)(wsb + ((size_t)18 << 20));   // 2 MB @18M
    bf16* ffh16 = att16;                               // 8 MB @12M (aliases attn bufs; disjoint lifetime)
    bf16* wts   = (bf16*)(wsb + ((size_t)20 << 20));   // 16 MB @20M
    const size_t WCH = 1048576;
    const size_t DD = (size_t)D * D;

    // ---- unified prep: all weight transposes + pos-enc + enc cvt (1 dispatch) ----
    prep_all<<<6144, 256, 0, stream>>>(a1w, a2w, fw1, fw2, wts, x, enc, xb, xb16, enc16);

    for (int l = 0; l < NLAYER; ++l) {
        const bf16* A1T = wts + (size_t)(0 + l) * WCH;
        const bf16* A2T = wts + (size_t)(2 + l) * WCH;
        const bf16* W1T = wts + (size_t)(4 + l) * WCH;
        const bf16* W2T = wts + (size_t)(6 + l) * WCH;
        const float* b1v = a1b + (size_t)l * 4 * D;
        const float* b2v = a2b + (size_t)l * 4 * D;

        // self-attention: fused QKV GEMM writes q16/kh16/vt16 directly
        gemm_bf16<64, 64, 64, 1><<<dim3(24, 32), 256, 0, stream>>>(
            xb16, xb16, A1T, b1v, nullptr, nullptr, D, 0, 0, q16, kh16, vt16, 512, 512);
        attn_mfma7<1><<<dim3(H, S / 64), 512, 0, stream>>>(q16, kh16, vt16, att16);
        gemm_bf16<32, 64, 64, 0><<<dim3(8, 64), 256, 0, stream>>>(
            att16, att16, A1T + 3 * DD, b1v + 3 * D, ao, nullptr, D, D, 0, nullptr, nullptr, nullptr, 0, 0);
        add_ln_kernel<<<S, 128, 0, stream>>>(xb, ao, lng + (size_t)(l * 3 + 0) * D, lnb + (size_t)(l * 3 + 0) * D, xb, xb16);

        // cross-attention: merged q|kv projection (A per region: q from xb16,
        // k/v from enc16), single full-machine dispatch
        gemm_bf16<64, 64, 64, 1><<<dim3(24, 32), 256, 0, stream>>>(
            xb16, enc16, A2T, b2v, nullptr, nullptr, D, 0, 0, q16, kh16, vt16, 512, 512);
        attn_mfma7<0><<<dim3(H, S / 64), 512, 0, stream>>>(q16, kh16, vt16, att16);
        gemm_bf16<32, 64, 64, 0><<<dim3(8, 64), 256, 0, stream>>>(
            att16, att16, A2T + 3 * DD, b2v + 3 * D, ao, nullptr, D, D, 0, nullptr, nullptr, nullptr, 0, 0);
        add_ln_kernel<<<S, 128, 0, stream>>>(xb, ao, lng + (size_t)(l * 3 + 1) * D, lnb + (size_t)(l * 3 + 1) * D, xb, xb16);

        // FFN
        gemm_bf16<64, 64, 64, 0><<<dim3(32, 32), 256, 0, stream>>>(
            xb16, xb16, W1T, fb1 + (size_t)l * F, nullptr, ffh16, D, F, 1, nullptr, nullptr, nullptr, 0, 0);
        gemm_bf16<32, 64, 64, 0><<<dim3(8, 64), 256, 0, stream>>>(
            ffh16, ffh16, W2T, fb2 + (size_t)l * D, ao, nullptr, F, D, 0, nullptr, nullptr, nullptr, 0, 0);
        float* dstF = (l == NLAYER - 1) ? out : xb;
        bf16* dstB = (l == NLAYER - 1) ? nullptr : xb16;
        add_ln_kernel<<<S, 128, 0, stream>>>(xb, ao, lng + (size_t)(l * 3 + 2) * D, lnb + (size_t)(l * 3 + 2) * D, dstF, dstB);
    }
}